// Round 1
// baseline (454.313 us; speedup 1.0000x reference)
//
#include <hip/hip_runtime.h>

#define H 4
#define C 128
#define FOUT 512
#define BM 64
#define BN 64

// ---------------- CSR build ----------------
__global__ void zero_i32(int* __restrict__ p, int n) {
    int i = blockIdx.x * blockDim.x + threadIdx.x;
    if (i < n) p[i] = 0;
}

__global__ void hist_kernel(const int* __restrict__ ei, int E, int N, int* __restrict__ counts) {
    int e = blockIdx.x * blockDim.x + threadIdx.x;
    int M = E + N;
    if (e >= M) return;
    int d = (e < E) ? ei[E + e] : (e - E);
    atomicAdd(&counts[d], 1);
}

__global__ __launch_bounds__(256) void scan_kernel(const int* __restrict__ counts,
                                                   int* __restrict__ row_off,
                                                   int* __restrict__ cursor, int N) {
    __shared__ int part[256];
    int t = threadIdx.x;
    int chunk = (N + 255) >> 8;
    int b = t * chunk; if (b > N) b = N;
    int e = b + chunk; if (e > N) e = N;
    int s = 0;
    for (int i = b; i < e; ++i) s += counts[i];
    part[t] = s;
    __syncthreads();
    for (int off = 1; off < 256; off <<= 1) {
        int v = (t >= off) ? part[t - off] : 0;
        __syncthreads();
        part[t] += v;
        __syncthreads();
    }
    int run = (t == 0) ? 0 : part[t - 1];
    for (int i = b; i < e; ++i) { row_off[i] = run; cursor[i] = run; run += counts[i]; }
    if (t == 255) row_off[N] = part[255];
}

__global__ void scatter_kernel(const int* __restrict__ ei, int E, int N,
                               int* __restrict__ cursor, int* __restrict__ csr_src) {
    int e = blockIdx.x * blockDim.x + threadIdx.x;
    int M = E + N;
    if (e >= M) return;
    int s = (e < E) ? ei[e] : (e - E);
    int d = (e < E) ? ei[E + e] : (e - E);
    int pos = atomicAdd(&cursor[d], 1);
    csr_src[pos] = s;
}

// ---------------- GEMM: C[N x 512] = A[N x 128] @ B[128 x 512] ----------------
__global__ __launch_bounds__(256) void gemm_k128(const float* __restrict__ A, int lda, int Nrows,
                                                 const float* __restrict__ B,
                                                 float* __restrict__ Cout) {
    __shared__ float As[BM * 132];   // stride 132 words: pad to break bank conflicts, keeps 8B align
    __shared__ float Bs[128 * BN];
    int t = threadIdx.x;
    int tx = t & 15, ty = t >> 4;
    int r0 = blockIdx.y * BM;
    int c0 = blockIdx.x * BN;

    // stage A tile (64 x 128) via float2 (layer-1 input is only 8B aligned: stride 130, offset 2)
    #pragma unroll
    for (int i = 0; i < 16; ++i) {
        int q = t + i * 256;      // float2 index; 64 float2 per row
        int row = q >> 6;
        int c2 = q & 63;
        float2 v = make_float2(0.f, 0.f);
        int gr = r0 + row;
        if (gr < Nrows) v = *(const float2*)&A[(size_t)gr * lda + c2 * 2];
        *(float2*)&As[row * 132 + c2 * 2] = v;
    }
    // stage B tile (128 x 64) via float4
    #pragma unroll
    for (int i = 0; i < 8; ++i) {
        int q = t + i * 256;      // float4 index; 16 float4 per row
        int k = q >> 4;
        int j4 = q & 15;
        float4 v = *(const float4*)&B[(size_t)k * FOUT + c0 + j4 * 4];
        *(float4*)&Bs[k * BN + j4 * 4] = v;
    }
    __syncthreads();

    float acc[4][4];
    #pragma unroll
    for (int i = 0; i < 4; ++i)
        #pragma unroll
        for (int j = 0; j < 4; ++j) acc[i][j] = 0.f;

    int ar = ty * 4;
    #pragma unroll 4
    for (int k = 0; k < 128; ++k) {
        float4 b4 = *(const float4*)&Bs[k * BN + tx * 4];
        #pragma unroll
        for (int i = 0; i < 4; ++i) {
            float a = As[(ar + i) * 132 + k];
            acc[i][0] += a * b4.x;
            acc[i][1] += a * b4.y;
            acc[i][2] += a * b4.z;
            acc[i][3] += a * b4.w;
        }
    }

    #pragma unroll
    for (int i = 0; i < 4; ++i) {
        int gr = r0 + ar + i;
        if (gr < Nrows) {
            float4 v = make_float4(acc[i][0], acc[i][1], acc[i][2], acc[i][3]);
            *(float4*)&Cout[(size_t)gr * FOUT + c0 + tx * 4] = v;
        }
    }
}

// ---------------- per-node attention coefficients ----------------
__global__ __launch_bounds__(256) void alpha_kernel(const float* __restrict__ xh,
                                                    const float* __restrict__ a_src,
                                                    const float* __restrict__ a_dst,
                                                    float* __restrict__ alpha_s,
                                                    float* __restrict__ alpha_d, int N) {
    int n = blockIdx.x;
    int t = threadIdx.x;
    int h = t >> 6, l = t & 63;
    const float* row = xh + (size_t)n * FOUT + h * C;
    float v0 = row[l], v1 = row[l + 64];
    float as = v0 * a_src[h * C + l] + v1 * a_src[h * C + l + 64];
    float ad = v0 * a_dst[h * C + l] + v1 * a_dst[h * C + l + 64];
    #pragma unroll
    for (int off = 32; off >= 1; off >>= 1) {
        as += __shfl_xor(as, off);
        ad += __shfl_xor(ad, off);
    }
    if (l == 0) {
        alpha_s[n * H + h] = as;
        alpha_d[n * H + h] = ad;
    }
}

// ---------------- per-node softmax-weighted aggregation ----------------
__global__ __launch_bounds__(256) void aggregate_kernel(const float* __restrict__ xh,
                                                        const float* __restrict__ alpha_s,
                                                        const float* __restrict__ alpha_d,
                                                        const int* __restrict__ row_off,
                                                        const int* __restrict__ csr_src,
                                                        const float* __restrict__ bias,
                                                        float* __restrict__ feats_out, int N) {
    int n = blockIdx.x;
    int t = threadIdx.x;
    int h = t >> 6, l = t & 63;
    int beg = row_off[n], end = row_off[n + 1];
    float ad = alpha_d[n * H + h];

    // pass 1: segment max of leaky-relu logits (wave-strided; self-loop guarantees >=1 edge)
    float mx = -1e30f;
    for (int e = beg + l; e < end; e += 64) {
        int s = csr_src[e];
        float lg = alpha_s[s * H + h] + ad;
        lg = (lg >= 0.f) ? lg : 0.2f * lg;
        mx = fmaxf(mx, lg);
    }
    #pragma unroll
    for (int off = 32; off >= 1; off >>= 1) mx = fmaxf(mx, __shfl_xor(mx, off));

    // pass 2: accumulate sum(w * xh[src]) and sum(w); normalize at end
    float acc0 = 0.f, acc1 = 0.f, den = 0.f;
    const float* xb = xh + h * C;
    for (int e = beg; e < end; ++e) {
        int s = csr_src[e];
        float lg = alpha_s[s * H + h] + ad;
        lg = (lg >= 0.f) ? lg : 0.2f * lg;
        float w = __expf(lg - mx);
        const float* r = xb + (size_t)s * FOUT;
        den += w;
        acc0 += w * r[l];
        acc1 += w * r[l + 64];
    }

    __shared__ float sac[H][128];
    float inv = 1.f / den;
    sac[h][l] = acc0 * inv;
    sac[h][l + 64] = acc1 * inv;
    __syncthreads();
    if (t < 128) {
        float v = 0.25f * (sac[0][t] + sac[1][t] + sac[2][t] + sac[3][t]) + bias[t];
        feats_out[(size_t)n * C + t] = v;
    }
}

// ---------------- pairwise scorer ----------------
__global__ __launch_bounds__(256) void pair_kernel(const float* __restrict__ feats,
                                                   const float* __restrict__ x,
                                                   const int* __restrict__ idx, int P,
                                                   const float* __restrict__ fc_w,
                                                   const float* __restrict__ fc_b,
                                                   float* __restrict__ out) {
    int p = blockIdx.x * 4 + (threadIdx.x >> 6);
    int l = threadIdx.x & 63;
    if (p >= P) return;
    int i0 = idx[p], i1 = idx[P + p];
    const float* f0 = feats + (size_t)i0 * C;
    const float* f1 = feats + (size_t)i1 * C;
    float s = f0[l] * f1[l] + f0[l + 64] * f1[l + 64];
    #pragma unroll
    for (int off = 32; off >= 1; off >>= 1) s += __shfl_xor(s, off);
    if (l == 0) {
        float dx = x[(size_t)i0 * 130] - x[(size_t)i1 * 130];
        float dy = x[(size_t)i0 * 130 + 1] - x[(size_t)i1 * 130 + 1];
        float pe = dx * dx + dy * dy;
        out[p] = fc_w[0] * s + fc_w[1] * pe + fc_b[0];
    }
}

extern "C" void kernel_launch(void* const* d_in, const int* in_sizes, int n_in,
                              void* d_out, int out_size, void* d_ws, size_t ws_size,
                              hipStream_t stream) {
    const float* x   = (const float*)d_in[0];
    const int*   ei  = (const int*)d_in[1];
    const int*   idx = (const int*)d_in[2];
    const float* W1  = (const float*)d_in[3];
    const float* as1 = (const float*)d_in[4];
    const float* ad1 = (const float*)d_in[5];
    const float* b1  = (const float*)d_in[6];
    const float* W2  = (const float*)d_in[7];
    const float* as2 = (const float*)d_in[8];
    const float* ad2 = (const float*)d_in[9];
    const float* b2  = (const float*)d_in[10];
    const float* fcw = (const float*)d_in[11];
    const float* fcb = (const float*)d_in[12];
    float* out = (float*)d_out;

    const int N = in_sizes[0] / 130;
    const int E = in_sizes[1] / 2;
    const int P = in_sizes[2] / 2;
    const int M = E + N;

    char* ws = (char*)d_ws;
    size_t off = 0;
    auto alloc = [&](size_t bytes) -> void* {
        void* p = ws + off;
        off += (bytes + 255) & ~(size_t)255;
        return p;
    };
    float* xh      = (float*)alloc((size_t)N * FOUT * 4);
    float* feats   = (float*)alloc((size_t)N * C * 4);
    float* alpha_s = (float*)alloc((size_t)N * H * 4);
    float* alpha_d = (float*)alloc((size_t)N * H * 4);
    int*   row_off = (int*)alloc((size_t)(N + 1) * 4);
    int*   cursor  = (int*)alloc((size_t)N * 4);
    int*   counts  = (int*)alloc((size_t)N * 4);
    int*   csr_src = (int*)alloc((size_t)M * 4);

    // CSR by dst (shared across both layers)
    zero_i32<<<(N + 255) / 256, 256, 0, stream>>>(counts, N);
    hist_kernel<<<(M + 255) / 256, 256, 0, stream>>>(ei, E, N, counts);
    scan_kernel<<<1, 256, 0, stream>>>(counts, row_off, cursor, N);
    scatter_kernel<<<(M + 255) / 256, 256, 0, stream>>>(ei, E, N, cursor, csr_src);

    dim3 ggrid(FOUT / BN, (N + BM - 1) / BM);

    // layer 1 (input = x[:, 2:130], row stride 130)
    gemm_k128<<<ggrid, 256, 0, stream>>>(x + 2, 130, N, W1, xh);
    alpha_kernel<<<N, 256, 0, stream>>>(xh, as1, ad1, alpha_s, alpha_d, N);
    aggregate_kernel<<<N, 256, 0, stream>>>(xh, alpha_s, alpha_d, row_off, csr_src, b1, feats, N);

    // layer 2
    gemm_k128<<<ggrid, 256, 0, stream>>>(feats, 128, N, W2, xh);
    alpha_kernel<<<N, 256, 0, stream>>>(xh, as2, ad2, alpha_s, alpha_d, N);
    aggregate_kernel<<<N, 256, 0, stream>>>(xh, alpha_s, alpha_d, row_off, csr_src, b2, feats, N);

    // pairwise output
    pair_kernel<<<(P + 3) / 4, 256, 0, stream>>>(feats, x, idx, P, fcw, fcb, out);
}

// Round 2
// 374.778 us; speedup vs baseline: 1.2122x; 1.2122x over previous
//
#include <hip/hip_runtime.h>

#define H 4
#define C 128
#define FOUT 512
#define GBM 128
#define GBN 128
#define GBK 32

// ---------------- CSR build ----------------
__global__ void zero_i32(int* __restrict__ p, int n) {
    int i = blockIdx.x * blockDim.x + threadIdx.x;
    if (i < n) p[i] = 0;
}

__global__ void hist_kernel(const int* __restrict__ ei, int E, int N, int* __restrict__ counts) {
    int e = blockIdx.x * blockDim.x + threadIdx.x;
    int M = E + N;
    if (e >= M) return;
    int d = (e < E) ? ei[E + e] : (e - E);
    atomicAdd(&counts[d], 1);
}

__global__ __launch_bounds__(256) void scan_kernel(const int* __restrict__ counts,
                                                   int* __restrict__ row_off,
                                                   int* __restrict__ cursor, int N) {
    __shared__ int part[256];
    int t = threadIdx.x;
    int chunk = (N + 255) >> 8;
    int b = t * chunk; if (b > N) b = N;
    int e = b + chunk; if (e > N) e = N;
    int s = 0;
    for (int i = b; i < e; ++i) s += counts[i];
    part[t] = s;
    __syncthreads();
    for (int off = 1; off < 256; off <<= 1) {
        int v = (t >= off) ? part[t - off] : 0;
        __syncthreads();
        part[t] += v;
        __syncthreads();
    }
    int run = (t == 0) ? 0 : part[t - 1];
    for (int i = b; i < e; ++i) { row_off[i] = run; cursor[i] = run; run += counts[i]; }
    if (t == 255) row_off[N] = part[255];
}

__global__ void scatter_kernel(const int* __restrict__ ei, int E, int N,
                               int* __restrict__ cursor, int* __restrict__ csr_src) {
    int e = blockIdx.x * blockDim.x + threadIdx.x;
    int M = E + N;
    if (e >= M) return;
    int s = (e < E) ? ei[e] : (e - E);
    int d = (e < E) ? ei[E + e] : (e - E);
    int pos = atomicAdd(&cursor[d], 1);
    csr_src[pos] = s;
}

// round-to-nearest-even f32 -> bf16 bits
__device__ __forceinline__ unsigned int f2bf_bits(float f) {
    unsigned int u = __float_as_uint(f);
    u += 0x7fffu + ((u >> 16) & 1u);
    return u >> 16;
}

// ---------------- GEMM: C[N x 512] = A[N x 128] @ B[128 x 512], 8x8 per thread ----------------
__global__ __launch_bounds__(256) void gemm_k128_v2(const float* __restrict__ A, int lda, int Nrows,
                                                    const float* __restrict__ B,
                                                    float* __restrict__ Cf,
                                                    unsigned short* __restrict__ Cb) {
    __shared__ float As[GBK][132];   // transposed: As[k][row]; stride 132 (16B-mult, 2-way-free reads)
    __shared__ float Bs[GBK][128];   // f4-swizzled: j' = j ^ ((j>>3)&3)
    int t = threadIdx.x;
    int tx = t & 15, ty = t >> 4;
    int r0 = blockIdx.y * GBM;
    int c0 = blockIdx.x * GBN;

    float acc[8][8];
    #pragma unroll
    for (int i = 0; i < 8; ++i)
        #pragma unroll
        for (int j = 0; j < 8; ++j) acc[i][j] = 0.f;

    int j0 = (2 * tx) ^ (((2 * tx) >> 3) & 3);
    int j1 = (2 * tx + 1) ^ (((2 * tx + 1) >> 3) & 3);

    for (int k0 = 0; k0 < 128; k0 += GBK) {
        // stage A tile (128 rows x 32 k) transposed; float2 granularity, 8 per thread
        #pragma unroll
        for (int i = 0; i < 8; ++i) {
            int q = t + i * 256;
            int row = q >> 4, c2 = q & 15;
            int gr = r0 + row;
            float2 v = make_float2(0.f, 0.f);
            if (gr < Nrows) v = *(const float2*)&A[(size_t)gr * lda + k0 + c2 * 2];
            As[c2 * 2][row] = v.x;
            As[c2 * 2 + 1][row] = v.y;
        }
        // stage B tile (32 k x 128 cols); float4, swizzled, 4 per thread
        #pragma unroll
        for (int i = 0; i < 4; ++i) {
            int q = t + i * 256;
            int kk = q >> 5, j = q & 31;
            float4 v = *(const float4*)&B[(size_t)(k0 + kk) * FOUT + c0 + j * 4];
            int js = j ^ ((j >> 3) & 3);
            *(float4*)&Bs[kk][js * 4] = v;
        }
        __syncthreads();

        #pragma unroll
        for (int kk = 0; kk < GBK; ++kk) {
            float4 a0 = *(const float4*)&As[kk][ty * 8];
            float4 a1 = *(const float4*)&As[kk][ty * 8 + 4];
            float4 b0 = *(const float4*)&Bs[kk][j0 * 4];
            float4 b1 = *(const float4*)&Bs[kk][j1 * 4];
            float av[8] = {a0.x, a0.y, a0.z, a0.w, a1.x, a1.y, a1.z, a1.w};
            float bv[8] = {b0.x, b0.y, b0.z, b0.w, b1.x, b1.y, b1.z, b1.w};
            #pragma unroll
            for (int i = 0; i < 8; ++i)
                #pragma unroll
                for (int j = 0; j < 8; ++j) acc[i][j] += av[i] * bv[j];
        }
        __syncthreads();
    }

    // epilogue: rows r0+ty*8+i, cols c0+tx*8.. ; write fp32 and bf16 copies
    #pragma unroll
    for (int i = 0; i < 8; ++i) {
        int gr = r0 + ty * 8 + i;
        if (gr < Nrows) {
            size_t base = (size_t)gr * FOUT + c0 + tx * 8;
            float4 v0 = make_float4(acc[i][0], acc[i][1], acc[i][2], acc[i][3]);
            float4 v1 = make_float4(acc[i][4], acc[i][5], acc[i][6], acc[i][7]);
            *(float4*)&Cf[base] = v0;
            *(float4*)&Cf[base + 4] = v1;
            uint4 u;
            u.x = f2bf_bits(acc[i][0]) | (f2bf_bits(acc[i][1]) << 16);
            u.y = f2bf_bits(acc[i][2]) | (f2bf_bits(acc[i][3]) << 16);
            u.z = f2bf_bits(acc[i][4]) | (f2bf_bits(acc[i][5]) << 16);
            u.w = f2bf_bits(acc[i][6]) | (f2bf_bits(acc[i][7]) << 16);
            *(uint4*)&Cb[base] = u;
        }
    }
}

// ---------------- per-node attention coefficients ----------------
__global__ __launch_bounds__(256) void alpha_kernel(const float* __restrict__ xh,
                                                    const float* __restrict__ a_src,
                                                    const float* __restrict__ a_dst,
                                                    float* __restrict__ alpha_s,
                                                    float* __restrict__ alpha_d, int N) {
    int n = blockIdx.x;
    int t = threadIdx.x;
    int h = t >> 6, l = t & 63;
    const float* row = xh + (size_t)n * FOUT + h * C;
    float v0 = row[l], v1 = row[l + 64];
    float as = v0 * a_src[h * C + l] + v1 * a_src[h * C + l + 64];
    float ad = v0 * a_dst[h * C + l] + v1 * a_dst[h * C + l + 64];
    #pragma unroll
    for (int off = 32; off >= 1; off >>= 1) {
        as += __shfl_xor(as, off);
        ad += __shfl_xor(ad, off);
    }
    if (l == 0) {
        alpha_s[n * H + h] = as;
        alpha_d[n * H + h] = ad;
    }
}

// ---------------- per-node softmax-weighted aggregation (bf16 gather, fp32 accum) ----------------
__global__ __launch_bounds__(256) void aggregate_v2(const unsigned short* __restrict__ xh_bf,
                                                    const float* __restrict__ alpha_s,
                                                    const float* __restrict__ alpha_d,
                                                    const int* __restrict__ row_off,
                                                    const int* __restrict__ csr_src,
                                                    const float* __restrict__ bias,
                                                    float* __restrict__ feats_out, int N) {
    int n = blockIdx.x;
    int t = threadIdx.x;
    int h = t >> 6, l = t & 63;
    int beg = row_off[n], end = row_off[n + 1];
    float ad = alpha_d[n * H + h];

    // pass 1: segment max of leaky-relu logits (self-loop guarantees >=1 edge)
    float mx = -1e30f;
    for (int e = beg + l; e < end; e += 64) {
        float lg = alpha_s[csr_src[e] * H + h] + ad;
        lg = (lg >= 0.f) ? lg : 0.2f * lg;
        mx = fmaxf(mx, lg);
    }
    #pragma unroll
    for (int off = 32; off >= 1; off >>= 1) mx = fmaxf(mx, __shfl_xor(mx, off));

    // pass 2: lane covers channels {2l, 2l+1} -> one dword bf16 load per edge per lane
    float acc0 = 0.f, acc1 = 0.f, den0 = 0.f;
    float acc2 = 0.f, acc3 = 0.f, den1 = 0.f;
    size_t choff = (size_t)(h * C + 2 * l);
    int e = beg;
    for (; e + 1 < end; e += 2) {
        int s0 = csr_src[e], s1 = csr_src[e + 1];
        unsigned int v0 = *(const unsigned int*)&xh_bf[(size_t)s0 * FOUT + choff];
        unsigned int v1 = *(const unsigned int*)&xh_bf[(size_t)s1 * FOUT + choff];
        float lg0 = alpha_s[s0 * H + h] + ad;
        float lg1 = alpha_s[s1 * H + h] + ad;
        lg0 = (lg0 >= 0.f) ? lg0 : 0.2f * lg0;
        lg1 = (lg1 >= 0.f) ? lg1 : 0.2f * lg1;
        float w0 = __expf(lg0 - mx);
        float w1 = __expf(lg1 - mx);
        den0 += w0; den1 += w1;
        acc0 += w0 * __uint_as_float(v0 << 16);
        acc1 += w0 * __uint_as_float(v0 & 0xffff0000u);
        acc2 += w1 * __uint_as_float(v1 << 16);
        acc3 += w1 * __uint_as_float(v1 & 0xffff0000u);
    }
    if (e < end) {
        int s0 = csr_src[e];
        unsigned int v0 = *(const unsigned int*)&xh_bf[(size_t)s0 * FOUT + choff];
        float lg0 = alpha_s[s0 * H + h] + ad;
        lg0 = (lg0 >= 0.f) ? lg0 : 0.2f * lg0;
        float w0 = __expf(lg0 - mx);
        den0 += w0;
        acc0 += w0 * __uint_as_float(v0 << 16);
        acc1 += w0 * __uint_as_float(v0 & 0xffff0000u);
    }
    float den = den0 + den1;
    float inv = 1.f / den;

    __shared__ float sac[H][128];
    *(float2*)&sac[h][2 * l] = make_float2((acc0 + acc2) * inv, (acc1 + acc3) * inv);
    __syncthreads();
    if (t < 128) {
        float v = 0.25f * (sac[0][t] + sac[1][t] + sac[2][t] + sac[3][t]) + bias[t];
        feats_out[(size_t)n * C + t] = v;
    }
}

// ---------------- pairwise scorer ----------------
__global__ __launch_bounds__(256) void pair_kernel(const float* __restrict__ feats,
                                                   const float* __restrict__ x,
                                                   const int* __restrict__ idx, int P,
                                                   const float* __restrict__ fc_w,
                                                   const float* __restrict__ fc_b,
                                                   float* __restrict__ out) {
    int p = blockIdx.x * 4 + (threadIdx.x >> 6);
    int l = threadIdx.x & 63;
    if (p >= P) return;
    int i0 = idx[p], i1 = idx[P + p];
    const float* f0 = feats + (size_t)i0 * C;
    const float* f1 = feats + (size_t)i1 * C;
    float s = f0[l] * f1[l] + f0[l + 64] * f1[l + 64];
    #pragma unroll
    for (int off = 32; off >= 1; off >>= 1) s += __shfl_xor(s, off);
    if (l == 0) {
        float dx = x[(size_t)i0 * 130] - x[(size_t)i1 * 130];
        float dy = x[(size_t)i0 * 130 + 1] - x[(size_t)i1 * 130 + 1];
        float pe = dx * dx + dy * dy;
        out[p] = fc_w[0] * s + fc_w[1] * pe + fc_b[0];
    }
}

extern "C" void kernel_launch(void* const* d_in, const int* in_sizes, int n_in,
                              void* d_out, int out_size, void* d_ws, size_t ws_size,
                              hipStream_t stream) {
    const float* x   = (const float*)d_in[0];
    const int*   ei  = (const int*)d_in[1];
    const int*   idx = (const int*)d_in[2];
    const float* W1  = (const float*)d_in[3];
    const float* as1 = (const float*)d_in[4];
    const float* ad1 = (const float*)d_in[5];
    const float* b1  = (const float*)d_in[6];
    const float* W2  = (const float*)d_in[7];
    const float* as2 = (const float*)d_in[8];
    const float* ad2 = (const float*)d_in[9];
    const float* b2  = (const float*)d_in[10];
    const float* fcw = (const float*)d_in[11];
    const float* fcb = (const float*)d_in[12];
    float* out = (float*)d_out;

    const int N = in_sizes[0] / 130;
    const int E = in_sizes[1] / 2;
    const int P = in_sizes[2] / 2;
    const int M = E + N;

    char* ws = (char*)d_ws;
    size_t off = 0;
    auto alloc = [&](size_t bytes) -> void* {
        void* p = ws + off;
        off += (bytes + 255) & ~(size_t)255;
        return p;
    };
    float*          xh      = (float*)alloc((size_t)N * FOUT * 4);
    unsigned short* xh_bf   = (unsigned short*)alloc((size_t)N * FOUT * 2);
    float*          feats   = (float*)alloc((size_t)N * C * 4);
    float*          alpha_s = (float*)alloc((size_t)N * H * 4);
    float*          alpha_d = (float*)alloc((size_t)N * H * 4);
    int*            row_off = (int*)alloc((size_t)(N + 1) * 4);
    int*            cursor  = (int*)alloc((size_t)N * 4);
    int*            counts  = (int*)alloc((size_t)N * 4);
    int*            csr_src = (int*)alloc((size_t)M * 4);

    // CSR by dst (shared across both layers)
    zero_i32<<<(N + 255) / 256, 256, 0, stream>>>(counts, N);
    hist_kernel<<<(M + 255) / 256, 256, 0, stream>>>(ei, E, N, counts);
    scan_kernel<<<1, 256, 0, stream>>>(counts, row_off, cursor, N);
    scatter_kernel<<<(M + 255) / 256, 256, 0, stream>>>(ei, E, N, cursor, csr_src);

    dim3 ggrid(FOUT / GBN, (N + GBM - 1) / GBM);

    // layer 1 (input = x[:, 2:130], row stride 130)
    gemm_k128_v2<<<ggrid, 256, 0, stream>>>(x + 2, 130, N, W1, xh, xh_bf);
    alpha_kernel<<<N, 256, 0, stream>>>(xh, as1, ad1, alpha_s, alpha_d, N);
    aggregate_v2<<<N, 256, 0, stream>>>(xh_bf, alpha_s, alpha_d, row_off, csr_src, b1, feats, N);

    // layer 2
    gemm_k128_v2<<<ggrid, 256, 0, stream>>>(feats, 128, N, W2, xh, xh_bf);
    alpha_kernel<<<N, 256, 0, stream>>>(xh, as2, ad2, alpha_s, alpha_d, N);
    aggregate_v2<<<N, 256, 0, stream>>>(xh_bf, alpha_s, alpha_d, row_off, csr_src, b2, feats, N);

    // pairwise output
    pair_kernel<<<(P + 3) / 4, 256, 0, stream>>>(feats, x, idx, P, fcw, fcb, out);
}

// Round 3
// 294.533 us; speedup vs baseline: 1.5425x; 1.2724x over previous
//
#include <hip/hip_runtime.h>

#define H 4
#define C 128
#define FOUT 512

typedef __attribute__((ext_vector_type(8))) short s16x8;
typedef __attribute__((ext_vector_type(4))) float f32x4;

__device__ __forceinline__ unsigned int f2bf_bits(float f) {
    unsigned int u = __float_as_uint(f);
    u += 0x7fffu + ((u >> 16) & 1u);
    return u >> 16;
}
__device__ __forceinline__ float bflo(unsigned int u) { return __uint_as_float(u << 16); }
__device__ __forceinline__ float bfhi(unsigned int u) { return __uint_as_float(u & 0xffff0000u); }
__device__ __forceinline__ float leaky(float x) { return (x >= 0.f) ? x : 0.2f * x; }

// ---------------- CSR build ----------------
__global__ void zero_i32(int* __restrict__ p, int n) {
    int i = blockIdx.x * blockDim.x + threadIdx.x;
    if (i < n) p[i] = 0;
}

__global__ void hist_kernel(const int* __restrict__ ei, int E, int N, int* __restrict__ counts) {
    int e = blockIdx.x * blockDim.x + threadIdx.x;
    int M = E + N;
    if (e >= M) return;
    int d = (e < E) ? ei[E + e] : (e - E);
    atomicAdd(&counts[d], 1);
}

__global__ __launch_bounds__(256) void scan_kernel(const int* __restrict__ counts,
                                                   int* __restrict__ row_off,
                                                   int* __restrict__ cursor, int N) {
    __shared__ int part[256];
    int t = threadIdx.x;
    int chunk = (N + 255) >> 8;
    int b = t * chunk; if (b > N) b = N;
    int e = b + chunk; if (e > N) e = N;
    int s = 0;
    for (int i = b; i < e; ++i) s += counts[i];
    part[t] = s;
    __syncthreads();
    for (int off = 1; off < 256; off <<= 1) {
        int v = (t >= off) ? part[t - off] : 0;
        __syncthreads();
        part[t] += v;
        __syncthreads();
    }
    int run = (t == 0) ? 0 : part[t - 1];
    for (int i = b; i < e; ++i) { row_off[i] = run; cursor[i] = run; run += counts[i]; }
    if (t == 255) row_off[N] = part[255];
}

__global__ void scatter_kernel(const int* __restrict__ ei, int E, int N,
                               int* __restrict__ cursor, int* __restrict__ csr_src,
                               int* __restrict__ slot) {
    int e = blockIdx.x * blockDim.x + threadIdx.x;
    int M = E + N;
    if (e >= M) return;
    int s = (e < E) ? ei[e] : (e - E);
    int d = (e < E) ? ei[E + e] : (e - E);
    int pos = atomicAdd(&cursor[d], 1);
    csr_src[pos] = s;
    slot[e] = pos;
}

// ---------------- input conversions ----------------
// x[:,2:130] (stride 130 fp32) -> xA bf16 [Npad][128], zero-padded rows; also zero featsbf tail
__global__ void convert_x(const float* __restrict__ x, unsigned short* __restrict__ xA,
                          unsigned short* __restrict__ featsbf, int N, int Npad) {
    int i = blockIdx.x * blockDim.x + threadIdx.x;  // one float4-group (4 ch) per thread
    int total = Npad * (C / 4);
    if (i >= total) return;
    int row = i >> 5;
    int c4 = (i & 31) * 4;
    ushort4 o;
    if (row < N) {
        const float* p = x + (size_t)row * 130 + 2 + c4;
        float2 v0 = *(const float2*)p;
        float2 v1 = *(const float2*)(p + 2);
        o.x = (unsigned short)f2bf_bits(v0.x);
        o.y = (unsigned short)f2bf_bits(v0.y);
        o.z = (unsigned short)f2bf_bits(v1.x);
        o.w = (unsigned short)f2bf_bits(v1.y);
    } else {
        o = make_ushort4(0, 0, 0, 0);
        *(ushort4*)&featsbf[(size_t)row * C + c4] = o;   // zero pad rows of layer-2 input
    }
    *(ushort4*)&xA[(size_t)row * C + c4] = o;
}

// W[k][c] (128x512 fp32) -> Wt[c][k] bf16 (512x128), for both layers
__global__ void convert_w(const float* __restrict__ W1, const float* __restrict__ W2,
                          unsigned short* __restrict__ Wt1, unsigned short* __restrict__ Wt2) {
    int i = blockIdx.x * blockDim.x + threadIdx.x;
    if (i >= 128 * 512) return;
    int c = i >> 7, k = i & 127;
    Wt1[i] = (unsigned short)f2bf_bits(W1[(size_t)k * FOUT + c]);
    Wt2[i] = (unsigned short)f2bf_bits(W2[(size_t)k * FOUT + c]);
}

// ---------------- MFMA GEMM + fused alpha ----------------
// C[N x 512] = A[N x 128] @ W[128 x 512]; block = (head h = 128 cols) x (128 rows)
// outputs: Cb bf16 xh; alpha_s/alpha_d [N][4]
__global__ __launch_bounds__(256) void gemm_mfma(const unsigned short* __restrict__ A,
                                                 const unsigned short* __restrict__ Bt,
                                                 const float* __restrict__ a_src,
                                                 const float* __restrict__ a_dst,
                                                 unsigned short* __restrict__ Cb,
                                                 float* __restrict__ alpha_s,
                                                 float* __restrict__ alpha_d,
                                                 int Nrows) {
    __shared__ unsigned short As[128 * 128];  // [row][k], 16B-chunk XOR-swizzled
    __shared__ unsigned short Bs[128 * 128];  // [colLocal][k], same swizzle
    int t = threadIdx.x;
    int lane = t & 63;
    int wv = t >> 6;
    int wr = wv >> 1, wc = wv & 1;
    int lr = lane & 15;
    int ksel = lane >> 4;
    int h = blockIdx.x;
    int r0 = blockIdx.y * 128;

    // stage A and Bt tiles (each 128x128 bf16 = 32KB), swizzle chunk index
    {
        const uint4* Ag = (const uint4*)(A + (size_t)r0 * C);
        const uint4* Bg = (const uint4*)(Bt + (size_t)h * 128 * C);
        uint4* AsV = (uint4*)As;
        uint4* BsV = (uint4*)Bs;
        #pragma unroll
        for (int i = 0; i < 8; ++i) {
            int q = t + i * 256;
            int row = q >> 4, cb = q & 15;
            AsV[row * 16 + (cb ^ (row & 7))] = Ag[q];
            BsV[row * 16 + (cb ^ (row & 7))] = Bg[q];
        }
    }
    __syncthreads();

    f32x4 acc[4][4];
    #pragma unroll
    for (int i = 0; i < 4; ++i)
        #pragma unroll
        for (int j = 0; j < 4; ++j) acc[i][j] = (f32x4){0.f, 0.f, 0.f, 0.f};

    #pragma unroll
    for (int ks = 0; ks < 4; ++ks) {
        int cb = ks * 4 + ksel;
        s16x8 af[4], bf[4];
        #pragma unroll
        for (int i = 0; i < 4; ++i) {
            int row = wr * 64 + i * 16 + lr;
            af[i] = *(const s16x8*)&As[row * C + (cb ^ (row & 7)) * 8];
            int col = wc * 64 + i * 16 + lr;
            bf[i] = *(const s16x8*)&Bs[col * C + (cb ^ (col & 7)) * 8];
        }
        #pragma unroll
        for (int i = 0; i < 4; ++i)
            #pragma unroll
            for (int j = 0; j < 4; ++j)
                acc[i][j] = __builtin_amdgcn_mfma_f32_16x16x32_bf16(af[i], bf[j], acc[i][j], 0, 0, 0);
    }
    __syncthreads();

    // transpose C frags (col-per-lane) into As as bf16 [row][col], byte-swizzled
    #pragma unroll
    for (int i = 0; i < 4; ++i) {
        #pragma unroll
        for (int j = 0; j < 4; ++j) {
            int col = wc * 64 + j * 16 + lr;
            #pragma unroll
            for (int r = 0; r < 4; ++r) {
                int row = wr * 64 + i * 16 + ksel * 4 + r;
                int boff = (row * 256 + col * 2) ^ ((row & 7) << 4);
                *(unsigned short*)((char*)As + boff) = (unsigned short)f2bf_bits(acc[i][j][r]);
            }
        }
    }
    __syncthreads();

    // coalesced store + fused alpha reduction
    int cb = t & 15, rb = t >> 4;
    float4 av0 = *(const float4*)&a_src[h * C + cb * 8];
    float4 av1 = *(const float4*)&a_src[h * C + cb * 8 + 4];
    float4 dv0 = *(const float4*)&a_dst[h * C + cb * 8];
    float4 dv1 = *(const float4*)&a_dst[h * C + cb * 8 + 4];
    #pragma unroll
    for (int i = 0; i < 8; ++i) {
        int row = rb + i * 16;
        uint4 v = ((const uint4*)As)[row * 16 + (cb ^ (row & 7))];
        float f0 = bflo(v.x), f1 = bfhi(v.x), f2 = bflo(v.y), f3 = bfhi(v.y);
        float f4 = bflo(v.z), f5 = bfhi(v.z), f6 = bflo(v.w), f7 = bfhi(v.w);
        float ps = f0 * av0.x + f1 * av0.y + f2 * av0.z + f3 * av0.w
                 + f4 * av1.x + f5 * av1.y + f6 * av1.z + f7 * av1.w;
        float pd = f0 * dv0.x + f1 * dv0.y + f2 * dv0.z + f3 * dv0.w
                 + f4 * dv1.x + f5 * dv1.y + f6 * dv1.z + f7 * dv1.w;
        ps += __shfl_xor(ps, 1); pd += __shfl_xor(pd, 1);
        ps += __shfl_xor(ps, 2); pd += __shfl_xor(pd, 2);
        ps += __shfl_xor(ps, 4); pd += __shfl_xor(pd, 4);
        ps += __shfl_xor(ps, 8); pd += __shfl_xor(pd, 8);
        int gr = r0 + row;
        if (gr < Nrows) {
            ((uint4*)Cb)[(size_t)gr * 64 + h * 16 + cb] = v;
            if (cb == 0) {
                alpha_s[gr * H + h] = ps;
                alpha_d[gr * H + h] = pd;
            }
        }
    }
}

// ---------------- per-node max (monotone leaky trick: m = leaky(max as + ad)) ----------------
__global__ __launch_bounds__(256) void max_kernel(const float4* __restrict__ as4,
                                                  const float4* __restrict__ ad4,
                                                  const int* __restrict__ row_off,
                                                  const int* __restrict__ csr_src,
                                                  float4* __restrict__ mbuf, int N) {
    int n = blockIdx.x * 4 + (threadIdx.x >> 6);
    if (n >= N) return;
    int l = threadIdx.x & 63;
    int beg = row_off[n], end = row_off[n + 1];
    float4 mx = make_float4(-1e30f, -1e30f, -1e30f, -1e30f);
    for (int e = beg + l; e < end; e += 64) {
        float4 a = as4[csr_src[e]];
        mx.x = fmaxf(mx.x, a.x); mx.y = fmaxf(mx.y, a.y);
        mx.z = fmaxf(mx.z, a.z); mx.w = fmaxf(mx.w, a.w);
    }
    #pragma unroll
    for (int off = 32; off >= 1; off >>= 1) {
        mx.x = fmaxf(mx.x, __shfl_xor(mx.x, off));
        mx.y = fmaxf(mx.y, __shfl_xor(mx.y, off));
        mx.z = fmaxf(mx.z, __shfl_xor(mx.z, off));
        mx.w = fmaxf(mx.w, __shfl_xor(mx.w, off));
    }
    if (l == 0) {
        float4 d = ad4[n];
        float4 m;
        m.x = leaky(mx.x + d.x); m.y = leaky(mx.y + d.y);
        m.z = leaky(mx.z + d.z); m.w = leaky(mx.w + d.w);
        mbuf[n] = m;
    }
}

// ---------------- per-edge softmax weights ----------------
__global__ void weight_kernel(const int* __restrict__ ei, const int* __restrict__ slot,
                              int E, int N,
                              const float4* __restrict__ as4, const float4* __restrict__ ad4,
                              const float4* __restrict__ m4, float4* __restrict__ wts) {
    int j = blockIdx.x * blockDim.x + threadIdx.x;
    int M = E + N;
    if (j >= M) return;
    int s = (j < E) ? ei[j] : (j - E);
    int d = (j < E) ? ei[E + j] : (j - E);
    float4 a = as4[s], b = ad4[d], m = m4[d];
    float4 w;
    w.x = __expf(leaky(a.x + b.x) - m.x);
    w.y = __expf(leaky(a.y + b.y) - m.y);
    w.z = __expf(leaky(a.z + b.z) - m.z);
    w.w = __expf(leaky(a.w + b.w) - m.w);
    wts[slot[j]] = w;
}

// ---------------- softmax-weighted aggregation (bf16 gather, precomputed w) ----------------
__global__ __launch_bounds__(256) void aggregate_v3(const unsigned short* __restrict__ xh_bf,
                                                    const float* __restrict__ wts,
                                                    const int* __restrict__ row_off,
                                                    const int* __restrict__ csr_src,
                                                    const float* __restrict__ bias,
                                                    float* __restrict__ feats_out,
                                                    unsigned short* __restrict__ feats_bf, int N) {
    int n = blockIdx.x;
    int t = threadIdx.x;
    int h = t >> 6, l = t & 63;
    int beg = row_off[n], end = row_off[n + 1];

    float acc0 = 0.f, acc1 = 0.f, den0 = 0.f;
    float acc2 = 0.f, acc3 = 0.f, den1 = 0.f;
    size_t choff = (size_t)(h * C + 2 * l);
    int e = beg;
    for (; e + 1 < end; e += 2) {
        int s0 = csr_src[e], s1 = csr_src[e + 1];
        float w0 = wts[e * H + h];
        float w1 = wts[(e + 1) * H + h];
        unsigned int v0 = *(const unsigned int*)&xh_bf[(size_t)s0 * FOUT + choff];
        unsigned int v1 = *(const unsigned int*)&xh_bf[(size_t)s1 * FOUT + choff];
        den0 += w0; den1 += w1;
        acc0 += w0 * bflo(v0); acc1 += w0 * bfhi(v0);
        acc2 += w1 * bflo(v1); acc3 += w1 * bfhi(v1);
    }
    if (e < end) {
        int s0 = csr_src[e];
        float w0 = wts[e * H + h];
        unsigned int v0 = *(const unsigned int*)&xh_bf[(size_t)s0 * FOUT + choff];
        den0 += w0;
        acc0 += w0 * bflo(v0); acc1 += w0 * bfhi(v0);
    }
    float inv = 1.f / (den0 + den1);

    __shared__ float sac[H][128];
    *(float2*)&sac[h][2 * l] = make_float2((acc0 + acc2) * inv, (acc1 + acc3) * inv);
    __syncthreads();
    if (t < 128) {
        float v = 0.25f * (sac[0][t] + sac[1][t] + sac[2][t] + sac[3][t]) + bias[t];
        feats_out[(size_t)n * C + t] = v;
        feats_bf[(size_t)n * C + t] = (unsigned short)f2bf_bits(v);
    }
}

// ---------------- pairwise scorer ----------------
__global__ __launch_bounds__(256) void pair_kernel(const float* __restrict__ feats,
                                                   const float* __restrict__ x,
                                                   const int* __restrict__ idx, int P,
                                                   const float* __restrict__ fc_w,
                                                   const float* __restrict__ fc_b,
                                                   float* __restrict__ out) {
    int p = blockIdx.x * 4 + (threadIdx.x >> 6);
    int l = threadIdx.x & 63;
    if (p >= P) return;
    int i0 = idx[p], i1 = idx[P + p];
    const float* f0 = feats + (size_t)i0 * C;
    const float* f1 = feats + (size_t)i1 * C;
    float s = f0[l] * f1[l] + f0[l + 64] * f1[l + 64];
    #pragma unroll
    for (int off = 32; off >= 1; off >>= 1) s += __shfl_xor(s, off);
    if (l == 0) {
        float dx = x[(size_t)i0 * 130] - x[(size_t)i1 * 130];
        float dy = x[(size_t)i0 * 130 + 1] - x[(size_t)i1 * 130 + 1];
        float pe = dx * dx + dy * dy;
        out[p] = fc_w[0] * s + fc_w[1] * pe + fc_b[0];
    }
}

extern "C" void kernel_launch(void* const* d_in, const int* in_sizes, int n_in,
                              void* d_out, int out_size, void* d_ws, size_t ws_size,
                              hipStream_t stream) {
    const float* x   = (const float*)d_in[0];
    const int*   ei  = (const int*)d_in[1];
    const int*   idx = (const int*)d_in[2];
    const float* W1  = (const float*)d_in[3];
    const float* as1 = (const float*)d_in[4];
    const float* ad1 = (const float*)d_in[5];
    const float* b1  = (const float*)d_in[6];
    const float* W2  = (const float*)d_in[7];
    const float* as2 = (const float*)d_in[8];
    const float* ad2 = (const float*)d_in[9];
    const float* b2  = (const float*)d_in[10];
    const float* fcw = (const float*)d_in[11];
    const float* fcb = (const float*)d_in[12];
    float* out = (float*)d_out;

    const int N = in_sizes[0] / 130;
    const int E = in_sizes[1] / 2;
    const int P = in_sizes[2] / 2;
    const int M = E + N;
    const int Npad = (N + 127) & ~127;

    char* ws = (char*)d_ws;
    size_t off = 0;
    auto alloc = [&](size_t bytes) -> void* {
        void* p = ws + off;
        off += (bytes + 255) & ~(size_t)255;
        return p;
    };
    unsigned short* xh_bf   = (unsigned short*)alloc((size_t)Npad * FOUT * 2);
    unsigned short* xA      = (unsigned short*)alloc((size_t)Npad * C * 2);
    unsigned short* featsbf = (unsigned short*)alloc((size_t)Npad * C * 2);
    float*          feats   = (float*)alloc((size_t)N * C * 4);
    unsigned short* Wt1     = (unsigned short*)alloc((size_t)128 * FOUT * 2);
    unsigned short* Wt2     = (unsigned short*)alloc((size_t)128 * FOUT * 2);
    float*          alpha_s = (float*)alloc((size_t)N * H * 4);
    float*          alpha_d = (float*)alloc((size_t)N * H * 4);
    float*          mbuf    = (float*)alloc((size_t)N * H * 4);
    float*          wts     = (float*)alloc((size_t)M * H * 4);
    int*            row_off = (int*)alloc((size_t)(N + 1) * 4);
    int*            cursor  = (int*)alloc((size_t)N * 4);
    int*            counts  = (int*)alloc((size_t)N * 4);
    int*            csr_src = (int*)alloc((size_t)M * 4);
    int*            slot    = (int*)alloc((size_t)M * 4);

    // CSR by dst (shared across both layers)
    zero_i32<<<(N + 255) / 256, 256, 0, stream>>>(counts, N);
    hist_kernel<<<(M + 255) / 256, 256, 0, stream>>>(ei, E, N, counts);
    scan_kernel<<<1, 256, 0, stream>>>(counts, row_off, cursor, N);
    scatter_kernel<<<(M + 255) / 256, 256, 0, stream>>>(ei, E, N, cursor, csr_src, slot);

    // input conversions
    convert_x<<<(Npad * (C / 4) + 255) / 256, 256, 0, stream>>>(x, xA, featsbf, N, Npad);
    convert_w<<<(128 * FOUT + 255) / 256, 256, 0, stream>>>(W1, W2, Wt1, Wt2);

    dim3 ggrid(H, Npad / 128);

    // layer 1
    gemm_mfma<<<ggrid, 256, 0, stream>>>(xA, Wt1, as1, ad1, xh_bf, alpha_s, alpha_d, N);
    max_kernel<<<(N + 3) / 4, 256, 0, stream>>>((const float4*)alpha_s, (const float4*)alpha_d,
                                                row_off, csr_src, (float4*)mbuf, N);
    weight_kernel<<<(M + 255) / 256, 256, 0, stream>>>(ei, slot, E, N, (const float4*)alpha_s,
                                                       (const float4*)alpha_d, (const float4*)mbuf,
                                                       (float4*)wts);
    aggregate_v3<<<N, 256, 0, stream>>>(xh_bf, wts, row_off, csr_src, b1, feats, featsbf, N);

    // layer 2
    gemm_mfma<<<ggrid, 256, 0, stream>>>(featsbf, Wt2, as2, ad2, xh_bf, alpha_s, alpha_d, N);
    max_kernel<<<(N + 3) / 4, 256, 0, stream>>>((const float4*)alpha_s, (const float4*)alpha_d,
                                                row_off, csr_src, (float4*)mbuf, N);
    weight_kernel<<<(M + 255) / 256, 256, 0, stream>>>(ei, slot, E, N, (const float4*)alpha_s,
                                                       (const float4*)alpha_d, (const float4*)mbuf,
                                                       (float4*)wts);
    aggregate_v3<<<N, 256, 0, stream>>>(xh_bf, wts, row_off, csr_src, b2, feats, featsbf, N);

    // pairwise output
    pair_kernel<<<(P + 3) / 4, 256, 0, stream>>>(feats, x, idx, P, fcw, fcb, out);
}